// Round 10
// baseline (80.187 us; speedup 1.0000x reference)
//
#include <hip/hip_runtime.h>

// Pfaffian of 128 gathered 128x128 skew-symmetric f32 matrices, Parlett-Reid
// LTL^T. One 1024-thread block per matrix.
//
// r27: BARRIER-FREE FLAG PIPELINE. r25 counters: core 21.2us = 1.33us/window
// vs bottom-up crew ~700cyc + bulk ~500cyc => ~1800cyc/window unexplained.
// r21/r22/r26 (SIMD rebalance, load batching, 2x waves) all neutral => bulk
// exonerated; residual must be barrier convergence/stagger + lockstep
// coupling. This round removes ALL window __syncthreads(), replacing them
// with two LDS semaphores that encode the exact dependency graph:
//   crew_done  : crew(Pn) published tau/col[Pn&1]  (bulk window P waits >=P)
//   bulk_done[P]: #active waves done reading/staging window P
//                 (crew(Pn) waits bulk_done[Pn-2]==14-(Pn-2) before
//                  overwriting set Pn&1 -- covers staging + WAR)
// Active waves at window P are exactly waves P+2..15 (14-P of them); wave w
// runs windows P=0..w-2 then EXITS (no barrier to hold retired waves).
// Wave 1 exits after the sort. All arithmetic and publication order
// unchanged -> absmax 0.0 expected.
//
// EVIDENCE LEDGER: core 21.2us, VALUBusy 13%, issue floor ~5us. Crew fma
// issue ~1.3cyc (r19). NEUTRAL/exonerated: crew pre-update cost (r15/16/18),
// SIMD contention + prologue (r21), bulk LDS reorder (r22), div count (r24),
// wave count/occupancy (r26). REGR: 16-wide panels (r19), shuffle chain
// (r23). rcp-mul taus == XLA trajectory (r24, absmax 0.0 certified).
//
// NUMERICS: tau = R * __fdiv_rn(1,piv);
//     tmp = fma(tau_r, col_c, A);  A' = fma(-col_r, tau_c, tmp)
// pf = __fmul_rn in step order. Dead indices exact 0.0f; stale cS rows
// masked (g <= k+1) before publication.
//
// PERF LEDGER (bench): r13 76.1 -> r24 77.31 (absmax 0.0) -> r25 diag
// (core 21.2us/rep pinned) -> r26 78.38 neutral. r27 predict 66-71 if
// barrier hypothesis right; neutral => crew-latency-bound -> head-racer
// surgery next on this barrier-free base.

#define POFF(i) ((i) + (((i) >> 5) << 2))   // 4-float pad every 32 floats
#define RL(v, l) __int_as_float(__builtin_amdgcn_readlane(__float_as_int(v), (l)))
#define WGSCOPE __HIP_MEMORY_SCOPE_WORKGROUP

__global__ __launch_bounds__(1024) void pfaffian_kernel(
    const float* __restrict__ x,    // [128, 128]
    const float* __restrict__ F,    // [32640] packed strict lower tri of 256x256
    float* __restrict__ out)        // [128]
{
    const int b    = blockIdx.x;
    const int t    = threadIdx.x;
    const int lane = t & 63;
    const int wave = t >> 6;        // 0..15

    __shared__ int idx_sh[128];
    __shared__ int wtot[4];
    __shared__ int crew_done;       // highest published panel index
    __shared__ int bulk_done[16];   // per-window completion counts
    __shared__ __align__(16) float tauLDS[2][4][144];
    __shared__ __align__(16) float colLDS[2][4][144];
    __shared__ __align__(16) float rS[2][4][144];   // panel row vecs k0,k0+2,k0+4,k0+6
    __shared__ __align__(16) float cS[2][4][144];   // panel col vecs k0+1,+3,+5,+7

    if (t == 0) crew_done = -1;
    if (t < 16) bulk_done[t] = 0;

    // ---- occupancy -> sorted index list (waves 0..3 do the work) ----
    if (t < 256) {
        const float xv  = x[b * 128 + (t & 127)];
        const bool  pos = xv > 0.0f;
        const bool  o   = (t < 128) ? pos : !pos;
        const unsigned long long mm = __ballot(o);
        const int rank = __popcll(mm & ((1ull << lane) - 1ull));
        if (lane == 63) wtot[wave] = rank + (o ? 1 : 0);
        __syncthreads();
        int off = 0;
#pragma unroll
        for (int w = 0; w < 4; ++w)
            if (w < wave) off += wtot[w];
        if (o) idx_sh[off + rank] = t;
    } else {
        __syncthreads();   // matches the barrier inside the t<256 branch
    }
    __syncthreads();       // idx_sh + flag init visible to all; LAST barrier

    // ---- 2x8 block ownership: wave w == panel w (rows 8w..8w+7) ----
    const int rg    = t >> 4;        // row-pair group 0..63: rows 2rg, 2rg+1
    const int cg    = t & 15;        // cols [cg*8, cg*8+8)
    const int col0  = cg << 3;
    const int prow2 = POFF(rg << 1);
    const int pcol  = POFF(col0);

    // raw A element (pre-elimination), same formula as the register gather
    auto Fval = [&](int gi, int gj) -> float {
        const int ii = idx_sh[gi];
        const int jj = idx_sh[gj];
        if (ii == jj) return 0.0f;                 // only hit when gi == gj
        const int hi = ii > jj ? ii : jj;
        const int lo = ii > jj ? jj : ii;
        const float v = F[(hi * (hi - 1)) / 2 + lo];
        return (ii < jj) ? -v : v;
    };

    float A[2][8];
    if (wave >= 2) {
        int ri[2], ci[8];
#pragma unroll
        for (int a = 0; a < 2; ++a) ri[a] = idx_sh[(rg << 1) + a];
#pragma unroll
        for (int c = 0; c < 8; ++c) ci[c] = idx_sh[col0 + c];
#pragma unroll
        for (int a = 0; a < 2; ++a) {
            const int ii = ri[a];
#pragma unroll
            for (int c = 0; c < 8; ++c) {
                const int jj = ci[c];
                const int hi = ii > jj ? ii : jj;
                const int lo = ii > jj ? jj : ii;
                float v = (ii == jj) ? 0.0f : F[(hi * (hi - 1)) / 2 + lo];
                A[a][c] = (ii < jj) ? -v : v;
            }
        }
    }

    // stage panel Pn into set st (active bulk waves; rS part by wave Pn only)
    auto stage = [&](int Pn, int st) {
        const int q = rg - 4 * Pn;          // 0..3 iff this thread is in wave Pn
        if (q >= 0 && q < 4) {
            *(float4*)&rS[st][q][pcol]     = make_float4(A[0][0], A[0][1], A[0][2], A[0][3]);
            *(float4*)&rS[st][q][pcol + 4] = make_float4(A[0][4], A[0][5], A[0][6], A[0][7]);
        }
        if (cg == Pn) {
            *(float2*)&cS[st][0][prow2] = make_float2(A[0][1], A[1][1]);
            *(float2*)&cS[st][1][prow2] = make_float2(A[0][3], A[1][3]);
            *(float2*)&cS[st][2][prow2] = make_float2(A[0][5], A[1][5]);
            *(float2*)&cS[st][3][prow2] = make_float2(A[0][7], A[1][7]);
        }
    };

    float pf = 1.0f;

    // crew for panel Pn (wave 0): pre-update with panel Pn-1 (if pre),
    // chain with rcp-mul taus, publish. UNCHANGED arithmetic (r24).
    auto crew2 = [&](int Pn, bool pre) {
        const int sv = Pn & 1;
        const int g0 = lane << 1;
        const int g1 = g0 + 1;
        const int pg = POFF(g0);
        float R[4][2], C[4][2];
#pragma unroll
        for (int j = 0; j < 4; ++j) {
            const float2 rv = *(const float2*)&rS[sv][j][pg];
            const float2 cv = *(const float2*)&cS[sv][j][pg];
            R[j][0] = rv.x; R[j][1] = rv.y;
            C[j][0] = cv.x; C[j][1] = cv.y;
        }
        if (pre) {
            const int svp  = sv ^ 1;
            const int base = POFF(8 * Pn);   // contiguous, inside one pad block
            float4 Tq[4][2], Cq[4][2];
#pragma unroll
            for (int jp = 0; jp < 4; ++jp) {   // batched broadcast loads
                Tq[jp][0] = *(const float4*)&tauLDS[svp][jp][base];
                Tq[jp][1] = *(const float4*)&tauLDS[svp][jp][base + 4];
                Cq[jp][0] = *(const float4*)&colLDS[svp][jp][base];
                Cq[jp][1] = *(const float4*)&colLDS[svp][jp][base + 4];
            }
#pragma unroll
            for (int jp = 0; jp < 4; ++jp) {
                const float trA[4] = {Tq[jp][0].x, Tq[jp][0].z, Tq[jp][1].x, Tq[jp][1].z};
                const float crA[4] = {Cq[jp][0].x, Cq[jp][0].z, Cq[jp][1].x, Cq[jp][1].z};
                const float tcA[4] = {Tq[jp][0].y, Tq[jp][0].w, Tq[jp][1].y, Tq[jp][1].w};
                const float ccA[4] = {Cq[jp][0].y, Cq[jp][0].w, Cq[jp][1].y, Cq[jp][1].w};
                const float2 tpv = *(const float2*)&tauLDS[svp][jp][pg];
                const float2 cpv = *(const float2*)&colLDS[svp][jp][pg];
#pragma unroll
                for (int a = 0; a < 4; ++a) {
                    const float tau_r = trA[a];
                    const float col_r = crA[a];
                    R[a][0] = __fmaf_rn(-col_r, tpv.x,
                              __fmaf_rn(tau_r, cpv.x, R[a][0]));
                    R[a][1] = __fmaf_rn(-col_r, tpv.y,
                              __fmaf_rn(tau_r, cpv.y, R[a][1]));
                    const float tau_c = tcA[a];
                    const float col_c = ccA[a];
                    C[a][0] = __fmaf_rn(-cpv.x, tau_c,
                              __fmaf_rn(tpv.x, col_c, C[a][0]));
                    C[a][1] = __fmaf_rn(-cpv.y, tau_c,
                              __fmaf_rn(tpv.y, col_c, C[a][1]));
                }
            }
        }
        float TAU[4][2], CV[4][2];
#pragma unroll
        for (int j = 0; j < 4; ++j) {
            const int k = 8 * Pn + 2 * j;
            const float piv = RL(R[j][1], 4 * Pn + j);
            pf = __fmul_rn(pf, piv);          // step order
            const float rp = __fdiv_rn(1.0f, piv);   // rcp-mul (r24, absmax 0.0)
            TAU[j][0] = (g0 > k + 1) ? __fmul_rn(R[j][0], rp) : 0.0f;
            TAU[j][1] = (g1 > k + 1) ? __fmul_rn(R[j][1], rp) : 0.0f;
            CV[j][0]  = (g0 > k + 1) ? C[j][0] : 0.0f;
            CV[j][1]  = (g1 > k + 1) ? C[j][1] : 0.0f;
            *(float2*)&tauLDS[sv][j][pg] = make_float2(TAU[j][0], TAU[j][1]);
            *(float2*)&colLDS[sv][j][pg] = make_float2(CV[j][0], CV[j][1]);
#pragma unroll
            for (int j2 = j + 1; j2 < 4; ++j2) {
                const int ls = 4 * Pn + j2;
                const float tau_r = RL(TAU[j][0], ls);
                const float col_r = RL(CV[j][0], ls);
                R[j2][0] = __fmaf_rn(-col_r, TAU[j][0],
                           __fmaf_rn(tau_r, CV[j][0], R[j2][0]));
                R[j2][1] = __fmaf_rn(-col_r, TAU[j][1],
                           __fmaf_rn(tau_r, CV[j][1], R[j2][1]));
                const float tau_c = RL(TAU[j][1], ls);
                const float col_c = RL(CV[j][1], ls);
                C[j2][0] = __fmaf_rn(-CV[j][0], tau_c,
                           __fmaf_rn(TAU[j][0], col_c, C[j2][0]));
                C[j2][1] = __fmaf_rn(-CV[j][1], tau_c,
                           __fmaf_rn(TAU[j][1], col_c, C[j2][1]));
            }
        }
    };

    if (wave == 0) {
        // ---- crew: prologue heads from F, crew(0), then 15 gated chains ----
        const int c0 = lane << 1;
        const int pc = POFF(c0);
#pragma unroll
        for (int st = 0; st < 2; ++st) {
#pragma unroll
            for (int j = 0; j < 4; ++j) {
                const int k = 8 * st + 2 * j;
                float2 rv, cv;
                rv.x = Fval(k, c0);
                rv.y = Fval(k, c0 + 1);
                cv.x = Fval(c0, k + 1);
                cv.y = Fval(c0 + 1, k + 1);
                *(float2*)&rS[st][j][pc] = rv;
                *(float2*)&cS[st][j][pc] = cv;
            }
        }
        crew2(0, false);
        __hip_atomic_store(&crew_done, 0, __ATOMIC_RELEASE, WGSCOPE);

        for (int Pn = 1; Pn <= 15; ++Pn) {
            if (Pn >= 2) {
                const int need = 14 - (Pn - 2);   // waves Pn..15
                while (__hip_atomic_load(&bulk_done[Pn - 2], __ATOMIC_ACQUIRE,
                                         WGSCOPE) < need) { }
            }
            crew2(Pn, true);
            __hip_atomic_store(&crew_done, Pn, __ATOMIC_RELEASE, WGSCOPE);
        }
        if (t == 0) out[b] = pf;
    } else if (wave >= 2) {
        // ---- bulk wave w: windows P = 0..w-2, then exit ----
        const int wlast = wave - 2;
        for (int P = 0; P <= wlast; ++P) {
            while (__hip_atomic_load(&crew_done, __ATOMIC_ACQUIRE,
                                     WGSCOPE) < P) { }
            const int sp = P & 1;
#pragma unroll
            for (int j = 0; j < 4; ++j) {
                const float2 trv = *(const float2*)&tauLDS[sp][j][prow2];
                const float2 crv = *(const float2*)&colLDS[sp][j][prow2];
                const float4 t0v = *(const float4*)&tauLDS[sp][j][pcol];
                const float4 t1v = *(const float4*)&tauLDS[sp][j][pcol + 4];
                const float4 c0v = *(const float4*)&colLDS[sp][j][pcol];
                const float4 c1v = *(const float4*)&colLDS[sp][j][pcol + 4];
                const float tr[2] = {trv.x, trv.y};
                const float cr[2] = {crv.x, crv.y};
                const float tc[8] = {t0v.x, t0v.y, t0v.z, t0v.w,
                                     t1v.x, t1v.y, t1v.z, t1v.w};
                const float cc[8] = {c0v.x, c0v.y, c0v.z, c0v.w,
                                     c1v.x, c1v.y, c1v.z, c1v.w};
#pragma unroll
                for (int a = 0; a < 2; ++a) {
#pragma unroll
                    for (int c = 0; c < 8; ++c) {
                        A[a][c] = __fmaf_rn(-cr[a], tc[c],
                                  __fmaf_rn(tr[a], cc[c], A[a][c]));
                    }
                }
            }
            stage(P + 2, sp);   // rS by wave P+2 (last iter); cS by cg==P+2
            if (lane == 0)
                __hip_atomic_fetch_add(&bulk_done[P], 1, __ATOMIC_RELEASE,
                                       WGSCOPE);
        }
    }
    // wave 1: nothing after the sort (its panel was staged by wave 0); exits.
}

extern "C" void kernel_launch(void* const* d_in, const int* in_sizes, int n_in,
                              void* d_out, int out_size, void* d_ws, size_t ws_size,
                              hipStream_t stream) {
    const float* x = (const float*)d_in[0];   // [128*128]
    const float* F = (const float*)d_in[1];   // [32640]
    float* out     = (float*)d_out;           // [128]
    (void)in_sizes; (void)n_in; (void)out_size; (void)d_ws; (void)ws_size;

    pfaffian_kernel<<<128, 1024, 0, stream>>>(x, F, out);
}